// Round 1
// baseline (109.340 us; speedup 1.0000x reference)
//
#include <hip/hip_runtime.h>

typedef __bf16 bf16;
typedef __bf16 bf16x8 __attribute__((ext_vector_type(8)));
typedef __bf16 bf16x4v __attribute__((ext_vector_type(4)));
typedef float  f32x4  __attribute__((ext_vector_type(4)));

#define NROWS 8192
#define DDIM  256
#define TAU_INV 2.0f
#define EPS 1e-8f

#define AS1C(p) ((const __attribute__((address_space(1))) void*)(p))
#define AS3(p)  ((__attribute__((address_space(3))) void*)(p))

// ---------------- cast fp32 -> bf16 (vectorized) ----------------
__global__ __launch_bounds__(256) void cast_f32_bf16(const float* __restrict__ src,
                                                     bf16* __restrict__ dst, int n4) {
  int i = blockIdx.x * blockDim.x + threadIdx.x;
  if (i < n4) {
    f32x4 v = ((const f32x4*)src)[i];
    bf16x4v o;
    o[0] = (bf16)v[0]; o[1] = (bf16)v[1]; o[2] = (bf16)v[2]; o[3] = (bf16)v[3];
    ((bf16x4v*)dst)[i] = o;
  }
}

// ---------------- fused 2-layer MLP + row-normalize ----------------
// grid (NROWS/64, 2), block 256. Per block: 64 rows, wave w owns rows [w*16, w*16+16).
// y = ELU(x@W1^T + b1) @ W2^T + b2 ; out = y / ||y||  (bf16 unit rows)
__global__ __launch_bounds__(256) void mlp_norm_kernel(
    const bf16* __restrict__ x1, const bf16* __restrict__ x2,
    const bf16* __restrict__ w1c, const float* __restrict__ b1c,
    const bf16* __restrict__ w2c, const float* __restrict__ b2c,
    const bf16* __restrict__ w1k, const float* __restrict__ b1k,
    const bf16* __restrict__ w2k, const float* __restrict__ b2k,
    bf16* __restrict__ outA, bf16* __restrict__ outB)
{
  const int view = blockIdx.y;
  const bf16*  x  = view ? x2  : x1;
  const bf16*  w1 = view ? w1k : w1c;
  const float* b1 = view ? b1k : b1c;
  const bf16*  w2 = view ? w2k : w2c;
  const float* b2 = view ? b2k : b2c;
  bf16* out = view ? outB : outA;

  __shared__ __align__(16) char xs[64 * 512];  // 64 rows x 256 bf16, XOR-swizzled

  const int tid  = threadIdx.x;
  const int lane = tid & 63;
  const int w    = tid >> 6;
  const int c    = lane & 15;
  const int g    = lane >> 4;
  const int r0   = blockIdx.x * 64;

  // stage x[r0:r0+64][0:256] -> xs ; linear LDS dest, inverse-swizzled global src
#pragma unroll
  for (int it = 0; it < 8; ++it) {
    int slot = it * 256 + tid;
    int row = slot >> 5, q = slot & 31;
    const bf16* src = x + (size_t)(r0 + row) * DDIM + ((q ^ (row & 7)) * 8);
    __builtin_amdgcn_global_load_lds(AS1C(src), AS3(xs + (it * 256 + w * 64) * 16), 16, 0, 0);
  }
  __syncthreads();

  float b1v[16], b2v[16];
#pragma unroll
  for (int ct = 0; ct < 16; ++ct) { b1v[ct] = b1[ct * 16 + c]; b2v[ct] = b2[ct * 16 + c]; }

  const int arow = w * 16 + c;          // A-fragment row (lane&15 = M index)
  const int aswz = (arow & 7) << 4;

  f32x4 acc[16];
  const f32x4 fz = {0.f, 0.f, 0.f, 0.f};
#pragma unroll
  for (int ct = 0; ct < 16; ++ct) acc[ct] = fz;

  // GEMM1: h_pre = x @ W1^T
#pragma unroll
  for (int ks = 0; ks < 8; ++ks) {
    bf16x8 af = *(const bf16x8*)(xs + arow * 512 + ((ks * 64 + g * 16) ^ aswz));
#pragma unroll
    for (int ct = 0; ct < 16; ++ct) {
      bf16x8 bfv = *(const bf16x8*)(w1 + (size_t)(ct * 16 + c) * DDIM + ks * 32 + g * 8);
      acc[ct] = __builtin_amdgcn_mfma_f32_16x16x32_bf16(af, bfv, acc[ct], 0, 0, 0);
    }
  }

  // ELU + write h back into xs (each wave writes only its own 16 rows)
#pragma unroll
  for (int ct = 0; ct < 16; ++ct) {
#pragma unroll
    for (int r = 0; r < 4; ++r) {
      float pre = acc[ct][r] + b1v[ct];
      float h = pre > 0.0f ? pre : (__expf(pre) - 1.0f);
      int row_l = w * 16 + g * 4 + r;
      int cb = (ct * 16 + c) * 2;
      *(bf16*)(xs + row_l * 512 + (cb ^ ((row_l & 7) << 4))) = (bf16)h;
    }
  }

#pragma unroll
  for (int ct = 0; ct < 16; ++ct) acc[ct] = fz;

  // GEMM2: z = h @ W2^T
#pragma unroll
  for (int ks = 0; ks < 8; ++ks) {
    bf16x8 af = *(const bf16x8*)(xs + arow * 512 + ((ks * 64 + g * 16) ^ aswz));
#pragma unroll
    for (int ct = 0; ct < 16; ++ct) {
      bf16x8 bfv = *(const bf16x8*)(w2 + (size_t)(ct * 16 + c) * DDIM + ks * 32 + g * 8);
      acc[ct] = __builtin_amdgcn_mfma_f32_16x16x32_bf16(af, bfv, acc[ct], 0, 0, 0);
    }
  }

  // bias + row-norm (rows = g*4+r ; cols spread over c-lanes and ct)
  float ss[4] = {0.f, 0.f, 0.f, 0.f};
#pragma unroll
  for (int ct = 0; ct < 16; ++ct)
#pragma unroll
    for (int r = 0; r < 4; ++r) {
      float z = acc[ct][r] + b2v[ct];
      acc[ct][r] = z;
      ss[r] += z * z;
    }
#pragma unroll
  for (int m = 1; m < 16; m <<= 1)
#pragma unroll
    for (int r = 0; r < 4; ++r) ss[r] += __shfl_xor(ss[r], m, 64);

  float rinv[4];
#pragma unroll
  for (int r = 0; r < 4; ++r) rinv[r] = 1.0f / sqrtf(ss[r]);

#pragma unroll
  for (int ct = 0; ct < 16; ++ct)
#pragma unroll
    for (int r = 0; r < 4; ++r) {
      int grow = r0 + w * 16 + g * 4 + r;
      out[(size_t)grow * DDIM + ct * 16 + c] = (bf16)(acc[ct][r] * rinv[r]);
    }
}

// ---------------- 128x128 tile: dot -> exp -> row partial sums ----------------
// grid (64 colblocks, 64 rowblocks), block 256 (4 waves, 2x2 of 64x64).
__global__ __launch_bounds__(256, 2) void lse_kernel(
    const bf16* __restrict__ A, const bf16* __restrict__ B, float* __restrict__ partial)
{
  __shared__ __align__(16) char As[128 * 128];  // 128 rows x 64 bf16, swizzled
  __shared__ __align__(16) char Bs[128 * 128];

  const int tid  = threadIdx.x;
  const int lane = tid & 63;
  const int w    = tid >> 6;
  const int c    = lane & 15;
  const int g    = lane >> 4;
  const int brow = blockIdx.y * 128;
  const int bcol = blockIdx.x * 128;
  const int wrow = (w >> 1) * 64;
  const int wcol = (w & 1) * 64;

  f32x4 acc[4][4];
  const f32x4 fz = {0.f, 0.f, 0.f, 0.f};
#pragma unroll
  for (int i = 0; i < 4; ++i)
#pragma unroll
    for (int j = 0; j < 4; ++j) acc[i][j] = fz;

  for (int kt = 0; kt < 4; ++kt) {
#pragma unroll
    for (int it = 0; it < 4; ++it) {
      int slot = it * 256 + tid;
      int row = slot >> 3, q = slot & 7;
      int col = kt * 64 + ((q ^ (row & 7)) * 8);
      __builtin_amdgcn_global_load_lds(AS1C(A + (size_t)(brow + row) * DDIM + col),
                                       AS3(As + (it * 256 + w * 64) * 16), 16, 0, 0);
      __builtin_amdgcn_global_load_lds(AS1C(B + (size_t)(bcol + row) * DDIM + col),
                                       AS3(Bs + (it * 256 + w * 64) * 16), 16, 0, 0);
    }
    __syncthreads();
#pragma unroll
    for (int sk = 0; sk < 2; ++sk) {
      bf16x8 af[4], bfv[4];
#pragma unroll
      for (int mt = 0; mt < 4; ++mt) {
        int rl = wrow + mt * 16 + c;
        af[mt] = *(const bf16x8*)(As + rl * 128 + ((sk * 64 + g * 16) ^ ((rl & 7) << 4)));
      }
#pragma unroll
      for (int ct = 0; ct < 4; ++ct) {
        int rl = wcol + ct * 16 + c;
        bfv[ct] = *(const bf16x8*)(Bs + rl * 128 + ((sk * 64 + g * 16) ^ ((rl & 7) << 4)));
      }
#pragma unroll
      for (int mt = 0; mt < 4; ++mt)
#pragma unroll
        for (int ct = 0; ct < 4; ++ct)
          acc[mt][ct] = __builtin_amdgcn_mfma_f32_16x16x32_bf16(af[mt], bfv[ct], acc[mt][ct], 0, 0, 0);
    }
    __syncthreads();
  }

  // epilogue: exp(2*dot), reduce over this wave's 64 cols
  float rs[4][4];
#pragma unroll
  for (int mt = 0; mt < 4; ++mt)
#pragma unroll
    for (int r = 0; r < 4; ++r) rs[mt][r] = 0.f;
#pragma unroll
  for (int mt = 0; mt < 4; ++mt)
#pragma unroll
    for (int ct = 0; ct < 4; ++ct)
#pragma unroll
      for (int r = 0; r < 4; ++r) rs[mt][r] += __expf(acc[mt][ct][r] * TAU_INV);
#pragma unroll
  for (int m = 1; m < 16; m <<= 1)
#pragma unroll
    for (int mt = 0; mt < 4; ++mt)
#pragma unroll
      for (int r = 0; r < 4; ++r) rs[mt][r] += __shfl_xor(rs[mt][r], m, 64);

  if (c == 0) {
    int cb2 = blockIdx.x * 2 + (w & 1);
#pragma unroll
    for (int mt = 0; mt < 4; ++mt)
#pragma unroll
      for (int r = 0; r < 4; ++r) {
        int grow = brow + wrow + mt * 16 + g * 4 + r;
        partial[(size_t)grow * 128 + cb2] = rs[mt][r];
      }
  }
}

// ---------------- per-row: sum partials + diag term ----------------
__global__ __launch_bounds__(256) void row_reduce_kernel(
    const float* __restrict__ partial, const bf16* __restrict__ A, const bf16* __restrict__ B,
    float* __restrict__ rowterm)
{
  int lane = threadIdx.x & 63;
  int w = threadIdx.x >> 6;
  int row = blockIdx.x * 4 + w;
  float s = partial[(size_t)row * 128 + lane] + partial[(size_t)row * 128 + 64 + lane];
  bf16x4v av = *(const bf16x4v*)(A + (size_t)row * DDIM + lane * 4);
  bf16x4v bv = *(const bf16x4v*)(B + (size_t)row * DDIM + lane * 4);
  float d = 0.f;
#pragma unroll
  for (int i = 0; i < 4; ++i) d += (float)av[i] * (float)bv[i];
#pragma unroll
  for (int m = 1; m < 64; m <<= 1) { s += __shfl_xor(s, m, 64); d += __shfl_xor(d, m, 64); }
  if (lane == 0) rowterm[row] = logf(s + EPS) - d * TAU_INV;
}

// ---------------- final mean ----------------
__global__ __launch_bounds__(256) void final_kernel(const float* __restrict__ rowterm,
                                                    float* __restrict__ out)
{
  __shared__ float part[4];
  int tid = threadIdx.x, lane = tid & 63, w = tid >> 6;
  float s = 0.f;
  for (int i = tid; i < NROWS; i += 256) s += rowterm[i];
#pragma unroll
  for (int m = 1; m < 64; m <<= 1) s += __shfl_xor(s, m, 64);
  if (lane == 0) part[w] = s;
  __syncthreads();
  if (tid == 0) out[0] = (part[0] + part[1] + part[2] + part[3]) * (1.0f / NROWS);
}

extern "C" void kernel_launch(void* const* d_in, const int* in_sizes, int n_in,
                              void* d_out, int out_size, void* d_ws, size_t ws_size,
                              hipStream_t stream) {
  const float* z1  = (const float*)d_in[0];
  const float* z2  = (const float*)d_in[1];
  const float* W1c = (const float*)d_in[2];
  const float* b1c = (const float*)d_in[3];
  const float* W2c = (const float*)d_in[4];
  const float* b2c = (const float*)d_in[5];
  const float* W1k = (const float*)d_in[6];
  const float* b1k = (const float*)d_in[7];
  const float* W2k = (const float*)d_in[8];
  const float* b2k = (const float*)d_in[9];

  char* ws = (char*)d_ws;
  bf16*  xb1     = (bf16*)(ws);
  bf16*  xb2     = (bf16*)(ws + (size_t)4  * 1024 * 1024);
  bf16*  aU      = (bf16*)(ws + (size_t)8  * 1024 * 1024);
  bf16*  bU      = (bf16*)(ws + (size_t)12 * 1024 * 1024);
  float* partial = (float*)(ws + (size_t)16 * 1024 * 1024);
  float* rowterm = (float*)(ws + (size_t)20 * 1024 * 1024);
  bf16*  w1cb    = (bf16*)(ws + (size_t)21 * 1024 * 1024);
  bf16*  w2cb    = (bf16*)(ws + (size_t)21 * 1024 * 1024 + 128 * 1024);
  bf16*  w1kb    = (bf16*)(ws + (size_t)21 * 1024 * 1024 + 256 * 1024);
  bf16*  w2kb    = (bf16*)(ws + (size_t)21 * 1024 * 1024 + 384 * 1024);

  int nz4 = NROWS * DDIM / 4;   // 524288
  int nw4 = DDIM * DDIM / 4;    // 16384
  cast_f32_bf16<<<nz4 / 256, 256, 0, stream>>>(z1, xb1, nz4);
  cast_f32_bf16<<<nz4 / 256, 256, 0, stream>>>(z2, xb2, nz4);
  cast_f32_bf16<<<nw4 / 256, 256, 0, stream>>>(W1c, w1cb, nw4);
  cast_f32_bf16<<<nw4 / 256, 256, 0, stream>>>(W2c, w2cb, nw4);
  cast_f32_bf16<<<nw4 / 256, 256, 0, stream>>>(W1k, w1kb, nw4);
  cast_f32_bf16<<<nw4 / 256, 256, 0, stream>>>(W2k, w2kb, nw4);

  mlp_norm_kernel<<<dim3(NROWS / 64, 2), 256, 0, stream>>>(
      xb1, xb2, w1cb, b1c, w2cb, b2c, w1kb, b1k, w2kb, b2k, aU, bU);

  lse_kernel<<<dim3(NROWS / 128, NROWS / 128), 256, 0, stream>>>(aU, bU, partial);

  row_reduce_kernel<<<NROWS / 4, 256, 0, stream>>>(partial, aU, bU, rowterm);
  final_kernel<<<1, 256, 0, stream>>>(rowterm, (float*)d_out);
}

// Round 2
// 104.959 us; speedup vs baseline: 1.0417x; 1.0417x over previous
//
#include <hip/hip_runtime.h>

typedef __bf16 bf16;
typedef __bf16 bf16x8 __attribute__((ext_vector_type(8)));
typedef __bf16 bf16x4v __attribute__((ext_vector_type(4)));
typedef float  f32x4  __attribute__((ext_vector_type(4)));

#define NROWS 8192
#define DDIM  256
#define TAU_INV 2.0f
#define EPS 1e-8f

#define AS1C(p) ((const __attribute__((address_space(1))) void*)(p))
#define AS3(p)  ((__attribute__((address_space(3))) void*)(p))

// ---------------- cast 4 weight matrices fp32 -> bf16 ----------------
__global__ __launch_bounds__(256) void cast4_kernel(
    const float* __restrict__ s0, const float* __restrict__ s1,
    const float* __restrict__ s2, const float* __restrict__ s3,
    bf16* __restrict__ dst) {
  const float* s = blockIdx.y == 0 ? s0 : blockIdx.y == 1 ? s1 : blockIdx.y == 2 ? s2 : s3;
  bf16* d = dst + (size_t)blockIdx.y * 65536;
  int i = blockIdx.x * 256 + threadIdx.x;      // 16384 f32x4 groups per matrix
  f32x4 v = ((const f32x4*)s)[i];
  bf16x4v o;
  o[0] = (bf16)v[0]; o[1] = (bf16)v[1]; o[2] = (bf16)v[2]; o[3] = (bf16)v[3];
  ((bf16x4v*)d)[i] = o;
}

// ---------------- fused cast + 2-layer MLP + row-normalize ----------------
// grid (NROWS/64, 2), block 256. Wave w owns rows [w*16, w*16+16).
__global__ __launch_bounds__(256) void mlp_norm_kernel(
    const float* __restrict__ z1f, const float* __restrict__ z2f,
    const bf16* __restrict__ wq,
    const float* __restrict__ b1c, const float* __restrict__ b2c,
    const float* __restrict__ b1k, const float* __restrict__ b2k,
    bf16* __restrict__ outA, bf16* __restrict__ outB)
{
  const int view = blockIdx.y;
  const float* xf = view ? z2f : z1f;
  const bf16*  w1 = wq + (size_t)view * 131072;
  const bf16*  w2 = w1 + 65536;
  const float* b1 = view ? b1k : b1c;
  const float* b2 = view ? b2k : b2c;
  bf16* out = view ? outB : outA;

  __shared__ __align__(16) char xs[64 * 512];  // 64 rows x 256 bf16, XOR-swizzled

  const int tid  = threadIdx.x;
  const int lane = tid & 63;
  const int w    = tid >> 6;
  const int c    = lane & 15;
  const int g    = lane >> 4;
  const int r0   = blockIdx.x * 64;

  // fused cast: load f32, convert, swizzled ds_write
#pragma unroll
  for (int k = 0; k < 8; ++k) {
    int gid = k * 256 + tid;
    int row = gid >> 5, cg = gid & 31;
    const f32x4* p = (const f32x4*)(xf + (size_t)(r0 + row) * DDIM + cg * 8);
    f32x4 v0 = p[0], v1 = p[1];
    bf16x8 o;
    o[0] = (bf16)v0[0]; o[1] = (bf16)v0[1]; o[2] = (bf16)v0[2]; o[3] = (bf16)v0[3];
    o[4] = (bf16)v1[0]; o[5] = (bf16)v1[1]; o[6] = (bf16)v1[2]; o[7] = (bf16)v1[3];
    *(bf16x8*)(xs + row * 512 + ((cg * 16) ^ ((row & 7) << 4))) = o;
  }
  __syncthreads();

  float b1v[16], b2v[16];
#pragma unroll
  for (int ct = 0; ct < 16; ++ct) { b1v[ct] = b1[ct * 16 + c]; b2v[ct] = b2[ct * 16 + c]; }

  const int arow = w * 16 + c;
  const int aswz = (arow & 7) << 4;

  f32x4 acc[16];
  const f32x4 fz = {0.f, 0.f, 0.f, 0.f};
#pragma unroll
  for (int ct = 0; ct < 16; ++ct) acc[ct] = fz;

  // GEMM1: h_pre = x @ W1^T
#pragma unroll
  for (int ks = 0; ks < 8; ++ks) {
    bf16x8 af = *(const bf16x8*)(xs + arow * 512 + ((ks * 64 + g * 16) ^ aswz));
#pragma unroll
    for (int ct = 0; ct < 16; ++ct) {
      bf16x8 bfv = *(const bf16x8*)(w1 + (size_t)(ct * 16 + c) * DDIM + ks * 32 + g * 8);
      acc[ct] = __builtin_amdgcn_mfma_f32_16x16x32_bf16(af, bfv, acc[ct], 0, 0, 0);
    }
  }

  // ELU + write h back into xs (each wave touches only its own 16 rows)
#pragma unroll
  for (int ct = 0; ct < 16; ++ct) {
#pragma unroll
    for (int r = 0; r < 4; ++r) {
      float pre = acc[ct][r] + b1v[ct];
      float h = pre > 0.0f ? pre : (__expf(pre) - 1.0f);
      int row_l = w * 16 + g * 4 + r;
      int cb = (ct * 16 + c) * 2;
      *(bf16*)(xs + row_l * 512 + (cb ^ ((row_l & 7) << 4))) = (bf16)h;
    }
  }

#pragma unroll
  for (int ct = 0; ct < 16; ++ct) acc[ct] = fz;

  // GEMM2: z = h @ W2^T
#pragma unroll
  for (int ks = 0; ks < 8; ++ks) {
    bf16x8 af = *(const bf16x8*)(xs + arow * 512 + ((ks * 64 + g * 16) ^ aswz));
#pragma unroll
    for (int ct = 0; ct < 16; ++ct) {
      bf16x8 bfv = *(const bf16x8*)(w2 + (size_t)(ct * 16 + c) * DDIM + ks * 32 + g * 8);
      acc[ct] = __builtin_amdgcn_mfma_f32_16x16x32_bf16(af, bfv, acc[ct], 0, 0, 0);
    }
  }

  float ss[4] = {0.f, 0.f, 0.f, 0.f};
#pragma unroll
  for (int ct = 0; ct < 16; ++ct)
#pragma unroll
    for (int r = 0; r < 4; ++r) {
      float z = acc[ct][r] + b2v[ct];
      acc[ct][r] = z;
      ss[r] += z * z;
    }
#pragma unroll
  for (int m = 1; m < 16; m <<= 1)
#pragma unroll
    for (int r = 0; r < 4; ++r) ss[r] += __shfl_xor(ss[r], m, 64);

  float rinv[4];
#pragma unroll
  for (int r = 0; r < 4; ++r) rinv[r] = 1.0f / sqrtf(ss[r]);

#pragma unroll
  for (int ct = 0; ct < 16; ++ct)
#pragma unroll
    for (int r = 0; r < 4; ++r) {
      int grow = r0 + w * 16 + g * 4 + r;
      out[(size_t)grow * DDIM + ct * 16 + c] = (bf16)(acc[ct][r] * rinv[r]);
    }
}

// ---------------- 256x256 tile, 8-wave, 4-phase/K-tile pipelined LSE ----------------
// grid (32, 32), block 512 (8 waves as 2x4; per-wave output 128x64).
// LDS: [buf][A:2x(128x64) | B:2x(128x64)] = 128 KiB, double-buffered over K-tiles.
__global__ __launch_bounds__(512, 2) void lse_kernel(
    const bf16* __restrict__ A, const bf16* __restrict__ B, float* __restrict__ partial)
{
  __shared__ __align__(16) char lds[131072];

  const int tid  = threadIdx.x;
  const int lane = tid & 63;
  const int w    = tid >> 6;          // 0..7
  const int c    = lane & 15;
  const int g    = lane >> 4;
  const int wm   = w >> 2;            // 0..1  (M half: rows wm*128..+128)
  const int wn   = w & 3;             // 0..3  (N chunk: cols wn*64..+64)
  const int brow = blockIdx.y * 256;
  const int bcol = blockIdx.x * 256;
  const int swz  = (c & 7) << 4;

  // stage half-tile h (128 rows x 64 cols) of matrix MAT (tile ttt) into LDS
#define STAGE(MAT, MATBASE, BASEROW, ttt, h)                                          \
  {                                                                                    \
    _Pragma("unroll")                                                                  \
    for (int l = 0; l < 2; ++l) {                                                      \
      int gran = l * 512 + tid;                                                        \
      int row = gran >> 3, q = gran & 7;                                               \
      const bf16* src = (MAT) + (size_t)((BASEROW) + (h) * 128 + row) * DDIM           \
                        + (ttt) * 64 + ((q ^ (row & 7)) << 3);                         \
      __builtin_amdgcn_global_load_lds(AS1C(src),                                      \
          AS3(lds + (((ttt) & 1) * 65536) + (MATBASE) + (h) * 16384                    \
              + (l * 512 + w * 64) * 16), 16, 0, 0);                                   \
    }                                                                                  \
  }

  f32x4 acc[8][4];
  const f32x4 fz = {0.f, 0.f, 0.f, 0.f};
#pragma unroll
  for (int i = 0; i < 8; ++i)
#pragma unroll
    for (int j = 0; j < 4; ++j) acc[i][j] = fz;

  // prologue: stage tile 0 fully, drain, barrier
  STAGE(A, 0,     brow, 0, 0); STAGE(A, 0,     brow, 0, 1);
  STAGE(B, 32768, bcol, 0, 0); STAGE(B, 32768, bcol, 0, 1);
  asm volatile("s_waitcnt vmcnt(0)" ::: "memory");
  __builtin_amdgcn_s_barrier();
  asm volatile("" ::: "memory");

  bf16x8 bfv[4];
#pragma unroll
  for (int t = 0; t < 4; ++t) {
    const int lbase = (t & 1) * 65536;
    const int abase = lbase + wm * 16384;
    const int bbase = lbase + 32768 + (wn >> 1) * 16384;
    const int brl   = (wn & 1) * 64;
#pragma unroll
    for (int p = 0; p < 4; ++p) {
      const int ks = p >> 1, mh = p & 1;
      // ds-load this phase's fragments
      bf16x8 af[4];
      if (mh == 0) {
#pragma unroll
        for (int nt = 0; nt < 4; ++nt)
          bfv[nt] = *(const bf16x8*)(lds + bbase + (brl + nt * 16 + c) * 128
                                     + ((ks * 64 + g * 16) ^ swz));
      }
#pragma unroll
      for (int i = 0; i < 4; ++i) {
        int mt = mh * 4 + i;
        af[i] = *(const bf16x8*)(lds + abase + (mt * 16 + c) * 128
                                 + ((ks * 64 + g * 16) ^ swz));
      }
      // prefetch next tile: A halves in phase 0, B halves in phase 1
      if (t < 3) {
        if (p == 0) { STAGE(A, 0,     brow, t + 1, 0); STAGE(A, 0,     brow, t + 1, 1); }
        if (p == 1) { STAGE(B, 32768, bcol, t + 1, 0); STAGE(B, 32768, bcol, t + 1, 1); }
      }
      __builtin_amdgcn_s_barrier();
      asm volatile("s_waitcnt lgkmcnt(0)" ::: "memory");
      __builtin_amdgcn_sched_barrier(0);
      __builtin_amdgcn_s_setprio(1);
#pragma unroll
      for (int i = 0; i < 4; ++i)
#pragma unroll
        for (int nt = 0; nt < 4; ++nt)
          acc[mh * 4 + i][nt] =
              __builtin_amdgcn_mfma_f32_16x16x32_bf16(af[i], bfv[nt], acc[mh * 4 + i][nt], 0, 0, 0);
      __builtin_amdgcn_s_setprio(0);
      if (p == 3 && t < 3) asm volatile("s_waitcnt vmcnt(0)" ::: "memory");
      __builtin_amdgcn_s_barrier();
      asm volatile("" ::: "memory");
    }
  }

  // epilogue: exp(2*dot), reduce over this wave's 64 cols
#pragma unroll
  for (int mt = 0; mt < 8; ++mt) {
    float rs[4] = {0.f, 0.f, 0.f, 0.f};
#pragma unroll
    for (int nt = 0; nt < 4; ++nt)
#pragma unroll
      for (int r = 0; r < 4; ++r) rs[r] += __expf(acc[mt][nt][r] * TAU_INV);
#pragma unroll
    for (int m = 1; m < 16; m <<= 1)
#pragma unroll
      for (int r = 0; r < 4; ++r) rs[r] += __shfl_xor(rs[r], m, 64);
    if (c == 0) {
#pragma unroll
      for (int r = 0; r < 4; ++r) {
        int grow = brow + wm * 128 + mt * 16 + g * 4 + r;
        partial[(size_t)grow * 128 + blockIdx.x * 4 + wn] = rs[r];
      }
    }
  }
#undef STAGE
}

// ---------------- per-row: sum partials + diag term ----------------
__global__ __launch_bounds__(256) void row_reduce_kernel(
    const float* __restrict__ partial, const bf16* __restrict__ A, const bf16* __restrict__ B,
    float* __restrict__ rowterm)
{
  int lane = threadIdx.x & 63;
  int w = threadIdx.x >> 6;
  int row = blockIdx.x * 4 + w;
  float s = partial[(size_t)row * 128 + lane] + partial[(size_t)row * 128 + 64 + lane];
  bf16x4v av = *(const bf16x4v*)(A + (size_t)row * DDIM + lane * 4);
  bf16x4v bv = *(const bf16x4v*)(B + (size_t)row * DDIM + lane * 4);
  float d = 0.f;
#pragma unroll
  for (int i = 0; i < 4; ++i) d += (float)av[i] * (float)bv[i];
#pragma unroll
  for (int m = 1; m < 64; m <<= 1) { s += __shfl_xor(s, m, 64); d += __shfl_xor(d, m, 64); }
  if (lane == 0) rowterm[row] = logf(s + EPS) - d * TAU_INV;
}

// ---------------- final mean ----------------
__global__ __launch_bounds__(256) void final_kernel(const float* __restrict__ rowterm,
                                                    float* __restrict__ out)
{
  __shared__ float part[4];
  int tid = threadIdx.x, lane = tid & 63, w = tid >> 6;
  float s = 0.f;
  for (int i = tid; i < NROWS; i += 256) s += rowterm[i];
#pragma unroll
  for (int m = 1; m < 64; m <<= 1) s += __shfl_xor(s, m, 64);
  if (lane == 0) part[w] = s;
  __syncthreads();
  if (tid == 0) out[0] = (part[0] + part[1] + part[2] + part[3]) * (1.0f / NROWS);
}

extern "C" void kernel_launch(void* const* d_in, const int* in_sizes, int n_in,
                              void* d_out, int out_size, void* d_ws, size_t ws_size,
                              hipStream_t stream) {
  const float* z1  = (const float*)d_in[0];
  const float* z2  = (const float*)d_in[1];
  const float* W1c = (const float*)d_in[2];
  const float* b1c = (const float*)d_in[3];
  const float* W2c = (const float*)d_in[4];
  const float* b2c = (const float*)d_in[5];
  const float* W1k = (const float*)d_in[6];
  const float* b1k = (const float*)d_in[7];
  const float* W2k = (const float*)d_in[8];
  const float* b2k = (const float*)d_in[9];

  char* ws = (char*)d_ws;
  bf16*  aU      = (bf16*)(ws);
  bf16*  bU      = (bf16*)(ws + (size_t)4  * 1024 * 1024);
  float* partial = (float*)(ws + (size_t)8  * 1024 * 1024);
  float* rowterm = (float*)(ws + (size_t)12 * 1024 * 1024);
  bf16*  wq      = (bf16*)(ws + (size_t)12 * 1024 * 1024 + 64 * 1024);

  // weights bf16: [W1c][W2c][W1k][W2k], 65536 elems each
  cast4_kernel<<<dim3(64, 4), 256, 0, stream>>>(W1c, W2c, W1k, W2k, wq);

  mlp_norm_kernel<<<dim3(NROWS / 64, 2), 256, 0, stream>>>(
      z1, z2, wq, b1c, b2c, b1k, b2k, aU, bU);

  lse_kernel<<<dim3(NROWS / 256, NROWS / 256), 512, 0, stream>>>(aU, bU, partial);

  row_reduce_kernel<<<NROWS / 4, 256, 0, stream>>>(partial, aU, bU, rowterm);
  final_kernel<<<1, 256, 0, stream>>>(rowterm, (float*)d_out);
}

// Round 3
// 103.172 us; speedup vs baseline: 1.0598x; 1.0173x over previous
//
#include <hip/hip_runtime.h>

typedef __bf16 bf16;
typedef __bf16 bf16x8 __attribute__((ext_vector_type(8)));
typedef __bf16 bf16x4v __attribute__((ext_vector_type(4)));
typedef float  f32x4  __attribute__((ext_vector_type(4)));

#define NROWS 8192
#define DDIM  256
#define TAU_INV 2.0f
#define EPS 1e-8f

#define AS1C(p) ((const __attribute__((address_space(1))) void*)(p))
#define AS3(p)  ((__attribute__((address_space(3))) void*)(p))

// ---------------- cast 4 weight matrices fp32 -> bf16 ----------------
__global__ __launch_bounds__(256) void cast4_kernel(
    const float* __restrict__ s0, const float* __restrict__ s1,
    const float* __restrict__ s2, const float* __restrict__ s3,
    bf16* __restrict__ dst) {
  const float* s = blockIdx.y == 0 ? s0 : blockIdx.y == 1 ? s1 : blockIdx.y == 2 ? s2 : s3;
  bf16* d = dst + (size_t)blockIdx.y * 65536;
  int i = blockIdx.x * 256 + threadIdx.x;
  f32x4 v = ((const f32x4*)s)[i];
  bf16x4v o;
  o[0] = (bf16)v[0]; o[1] = (bf16)v[1]; o[2] = (bf16)v[2]; o[3] = (bf16)v[3];
  ((bf16x4v*)d)[i] = o;
}

// ---------------- fused cast + 2-layer MLP + row-normalize ----------------
// grid (NROWS/64, 2), block 256. Wave w owns rows [w*16, w*16+16).
__global__ __launch_bounds__(256) void mlp_norm_kernel(
    const float* __restrict__ z1f, const float* __restrict__ z2f,
    const bf16* __restrict__ wq,
    const float* __restrict__ b1c, const float* __restrict__ b2c,
    const float* __restrict__ b1k, const float* __restrict__ b2k,
    bf16* __restrict__ outA, bf16* __restrict__ outB)
{
  const int view = blockIdx.y;
  const float* xf = view ? z2f : z1f;
  const bf16*  w1 = wq + (size_t)view * 131072;
  const bf16*  w2 = w1 + 65536;
  const float* b1 = view ? b1k : b1c;
  const float* b2 = view ? b2k : b2c;
  bf16* out = view ? outB : outA;

  __shared__ __align__(16) char xs[64 * 512];  // 64 rows x 256 bf16, XOR-swizzled

  const int tid  = threadIdx.x;
  const int lane = tid & 63;
  const int w    = tid >> 6;
  const int c    = lane & 15;
  const int g    = lane >> 4;
  const int r0   = blockIdx.x * 64;

#pragma unroll
  for (int k = 0; k < 8; ++k) {
    int gid = k * 256 + tid;
    int row = gid >> 5, cg = gid & 31;
    const f32x4* p = (const f32x4*)(xf + (size_t)(r0 + row) * DDIM + cg * 8);
    f32x4 v0 = p[0], v1 = p[1];
    bf16x8 o;
    o[0] = (bf16)v0[0]; o[1] = (bf16)v0[1]; o[2] = (bf16)v0[2]; o[3] = (bf16)v0[3];
    o[4] = (bf16)v1[0]; o[5] = (bf16)v1[1]; o[6] = (bf16)v1[2]; o[7] = (bf16)v1[3];
    *(bf16x8*)(xs + row * 512 + ((cg * 16) ^ ((row & 7) << 4))) = o;
  }
  __syncthreads();

  float b1v[16], b2v[16];
#pragma unroll
  for (int ct = 0; ct < 16; ++ct) { b1v[ct] = b1[ct * 16 + c]; b2v[ct] = b2[ct * 16 + c]; }

  const int arow = w * 16 + c;
  const int aswz = (arow & 7) << 4;

  f32x4 acc[16];
  const f32x4 fz = {0.f, 0.f, 0.f, 0.f};
#pragma unroll
  for (int ct = 0; ct < 16; ++ct) acc[ct] = fz;

#pragma unroll
  for (int ks = 0; ks < 8; ++ks) {
    bf16x8 af = *(const bf16x8*)(xs + arow * 512 + ((ks * 64 + g * 16) ^ aswz));
#pragma unroll
    for (int ct = 0; ct < 16; ++ct) {
      bf16x8 bfv = *(const bf16x8*)(w1 + (size_t)(ct * 16 + c) * DDIM + ks * 32 + g * 8);
      acc[ct] = __builtin_amdgcn_mfma_f32_16x16x32_bf16(af, bfv, acc[ct], 0, 0, 0);
    }
  }

#pragma unroll
  for (int ct = 0; ct < 16; ++ct) {
#pragma unroll
    for (int r = 0; r < 4; ++r) {
      float pre = acc[ct][r] + b1v[ct];
      float h = pre > 0.0f ? pre : (__expf(pre) - 1.0f);
      int row_l = w * 16 + g * 4 + r;
      int cb = (ct * 16 + c) * 2;
      *(bf16*)(xs + row_l * 512 + (cb ^ ((row_l & 7) << 4))) = (bf16)h;
    }
  }

#pragma unroll
  for (int ct = 0; ct < 16; ++ct) acc[ct] = fz;

#pragma unroll
  for (int ks = 0; ks < 8; ++ks) {
    bf16x8 af = *(const bf16x8*)(xs + arow * 512 + ((ks * 64 + g * 16) ^ aswz));
#pragma unroll
    for (int ct = 0; ct < 16; ++ct) {
      bf16x8 bfv = *(const bf16x8*)(w2 + (size_t)(ct * 16 + c) * DDIM + ks * 32 + g * 8);
      acc[ct] = __builtin_amdgcn_mfma_f32_16x16x32_bf16(af, bfv, acc[ct], 0, 0, 0);
    }
  }

  float ss[4] = {0.f, 0.f, 0.f, 0.f};
#pragma unroll
  for (int ct = 0; ct < 16; ++ct)
#pragma unroll
    for (int r = 0; r < 4; ++r) {
      float z = acc[ct][r] + b2v[ct];
      acc[ct][r] = z;
      ss[r] += z * z;
    }
#pragma unroll
  for (int m = 1; m < 16; m <<= 1)
#pragma unroll
    for (int r = 0; r < 4; ++r) ss[r] += __shfl_xor(ss[r], m, 64);

  float rinv[4];
#pragma unroll
  for (int r = 0; r < 4; ++r) rinv[r] = 1.0f / sqrtf(ss[r]);

#pragma unroll
  for (int ct = 0; ct < 16; ++ct)
#pragma unroll
    for (int r = 0; r < 4; ++r) {
      int grow = r0 + w * 16 + g * 4 + r;
      out[(size_t)grow * DDIM + ct * 16 + c] = (bf16)(acc[ct][r] * rinv[r]);
    }
}

// ---------------- 128x128 tile LSE, double-buffered, counted vmcnt ----------------
// grid 4096 (1D, XCD-swizzled to (bx,by)), block 256 (4 waves, 2x2 of 64x64).
// LDS: 2 bufs x (A 16KB | B 16KB) = 64 KiB -> 2 blocks/CU.
__global__ __launch_bounds__(256, 2) void lse_kernel(
    const bf16* __restrict__ A, const bf16* __restrict__ B, float* __restrict__ partial)
{
  __shared__ __align__(16) char lds[65536];

  const int fid = blockIdx.x;
  const int xcd = fid & 7;
  const int lid = fid >> 3;
  const int by  = xcd * 8 + (lid >> 6);   // row-band per XCD -> A panel L2-resident
  const int bx  = lid & 63;

  const int tid  = threadIdx.x;
  const int lane = tid & 63;
  const int w    = tid >> 6;
  const int c    = lane & 15;
  const int g    = lane >> 4;
  const int brow = by * 128;
  const int bcol = bx * 128;
  const int wrow = (w >> 1) * 64;
  const int wcol = (w & 1) * 64;
  const int swz  = (c & 7) << 4;

  // stage K-tile ttt into buffer (ttt&1): 8 gload_lds per thread, issue order A,B,A,B...
#define STAGE(ttt)                                                                     \
  {                                                                                    \
    const int bsel = ((ttt) & 1) * 32768;                                              \
    _Pragma("unroll")                                                                  \
    for (int it = 0; it < 4; ++it) {                                                   \
      int slot = it * 256 + tid;                                                       \
      int row = slot >> 3, q = slot & 7;                                               \
      int col = (ttt) * 64 + ((q ^ (row & 7)) << 3);                                   \
      __builtin_amdgcn_global_load_lds(AS1C(A + (size_t)(brow + row) * DDIM + col),    \
          AS3(lds + bsel + (it * 256 + w * 64) * 16), 16, 0, 0);                       \
      __builtin_amdgcn_global_load_lds(AS1C(B + (size_t)(bcol + row) * DDIM + col),    \
          AS3(lds + bsel + 16384 + (it * 256 + w * 64) * 16), 16, 0, 0);               \
    }                                                                                  \
  }

  f32x4 acc[4][4];
  const f32x4 fz = {0.f, 0.f, 0.f, 0.f};
#pragma unroll
  for (int i = 0; i < 4; ++i)
#pragma unroll
    for (int j = 0; j < 4; ++j) acc[i][j] = fz;

  STAGE(0);  // prologue: tile 0 in flight (8 loads outstanding)

#pragma unroll
  for (int t = 0; t < 4; ++t) {
    // barrier 1: all waves done READING buf[(t+1)&1] (compute of tile t-1)
    __builtin_amdgcn_s_barrier();
    asm volatile("" ::: "memory");
    if (t < 3) {
      STAGE(t + 1);  // prefetch into buf[(t+1)&1]; outstanding -> 16
      asm volatile("s_waitcnt vmcnt(8)" ::: "memory");  // tile t's 8 landed; t+1 in flight
    } else {
      asm volatile("s_waitcnt vmcnt(0)" ::: "memory");  // tile 3: issued one phase ago
    }
    // barrier 2: every wave's slice of tile t is in LDS
    __builtin_amdgcn_s_barrier();
    asm volatile("" ::: "memory");

    const int bsel = (t & 1) * 32768;
#pragma unroll
    for (int sk = 0; sk < 2; ++sk) {
      bf16x8 af[4], bfv[4];
#pragma unroll
      for (int mt = 0; mt < 4; ++mt)
        af[mt] = *(const bf16x8*)(lds + bsel + (wrow + mt * 16 + c) * 128
                                  + ((sk * 64 + g * 16) ^ swz));
#pragma unroll
      for (int nt = 0; nt < 4; ++nt)
        bfv[nt] = *(const bf16x8*)(lds + bsel + 16384 + (wcol + nt * 16 + c) * 128
                                   + ((sk * 64 + g * 16) ^ swz));
#pragma unroll
      for (int mt = 0; mt < 4; ++mt)
#pragma unroll
        for (int nt = 0; nt < 4; ++nt)
          acc[mt][nt] = __builtin_amdgcn_mfma_f32_16x16x32_bf16(af[mt], bfv[nt], acc[mt][nt], 0, 0, 0);
    }
  }
#undef STAGE

  // epilogue: exp(2*dot), reduce over this wave's 64 cols
  float rs[4][4];
#pragma unroll
  for (int mt = 0; mt < 4; ++mt)
#pragma unroll
    for (int r = 0; r < 4; ++r) rs[mt][r] = 0.f;
#pragma unroll
  for (int mt = 0; mt < 4; ++mt)
#pragma unroll
    for (int nt = 0; nt < 4; ++nt)
#pragma unroll
      for (int r = 0; r < 4; ++r) rs[mt][r] += __expf(acc[mt][nt][r] * TAU_INV);
#pragma unroll
  for (int m = 1; m < 16; m <<= 1)
#pragma unroll
    for (int mt = 0; mt < 4; ++mt)
#pragma unroll
      for (int r = 0; r < 4; ++r) rs[mt][r] += __shfl_xor(rs[mt][r], m, 64);

  if (c == 0) {
    int cb2 = bx * 2 + (w & 1);
#pragma unroll
    for (int mt = 0; mt < 4; ++mt)
#pragma unroll
      for (int r = 0; r < 4; ++r) {
        int grow = brow + wrow + mt * 16 + g * 4 + r;
        partial[(size_t)grow * 128 + cb2] = rs[mt][r];
      }
  }
}

// ---------------- per-row: sum partials + diag; per-block sum ----------------
// grid 128, block 256: block handles 64 rows (wave w: 16 rows serially).
__global__ __launch_bounds__(256) void row_reduce_kernel(
    const float* __restrict__ partial, const bf16* __restrict__ A, const bf16* __restrict__ B,
    float* __restrict__ blocksum)
{
  const int lane = threadIdx.x & 63;
  const int w    = threadIdx.x >> 6;
  float bsum = 0.f;
#pragma unroll 4
  for (int i = 0; i < 16; ++i) {
    int row = blockIdx.x * 64 + w * 16 + i;
    float s = partial[(size_t)row * 128 + lane] + partial[(size_t)row * 128 + 64 + lane];
    bf16x4v av = *(const bf16x4v*)(A + (size_t)row * DDIM + lane * 4);
    bf16x4v bv = *(const bf16x4v*)(B + (size_t)row * DDIM + lane * 4);
    float d = 0.f;
#pragma unroll
    for (int j = 0; j < 4; ++j) d += (float)av[j] * (float)bv[j];
#pragma unroll
    for (int m = 1; m < 64; m <<= 1) { s += __shfl_xor(s, m, 64); d += __shfl_xor(d, m, 64); }
    if (lane == 0) bsum += logf(s + EPS) - d * TAU_INV;
  }
  __shared__ float part[4];
  if (lane == 0) part[w] = bsum;
  __syncthreads();
  if (threadIdx.x == 0) blocksum[blockIdx.x] = part[0] + part[1] + part[2] + part[3];
}

// ---------------- final mean over 128 block sums ----------------
__global__ __launch_bounds__(128) void final_kernel(const float* __restrict__ blocksum,
                                                    float* __restrict__ out)
{
  int tid = threadIdx.x;
  float s = blocksum[tid];
#pragma unroll
  for (int m = 1; m < 64; m <<= 1) s += __shfl_xor(s, m, 64);
  __shared__ float p[2];
  if ((tid & 63) == 0) p[tid >> 6] = s;
  __syncthreads();
  if (tid == 0) out[0] = (p[0] + p[1]) * (1.0f / NROWS);
}

extern "C" void kernel_launch(void* const* d_in, const int* in_sizes, int n_in,
                              void* d_out, int out_size, void* d_ws, size_t ws_size,
                              hipStream_t stream) {
  const float* z1  = (const float*)d_in[0];
  const float* z2  = (const float*)d_in[1];
  const float* W1c = (const float*)d_in[2];
  const float* b1c = (const float*)d_in[3];
  const float* W2c = (const float*)d_in[4];
  const float* b2c = (const float*)d_in[5];
  const float* W1k = (const float*)d_in[6];
  const float* b1k = (const float*)d_in[7];
  const float* W2k = (const float*)d_in[8];
  const float* b2k = (const float*)d_in[9];

  char* ws = (char*)d_ws;
  bf16*  aU       = (bf16*)(ws);
  bf16*  bU       = (bf16*)(ws + (size_t)4  * 1024 * 1024);
  float* partial  = (float*)(ws + (size_t)8  * 1024 * 1024);
  float* blocksum = (float*)(ws + (size_t)12 * 1024 * 1024);
  bf16*  wq       = (bf16*)(ws + (size_t)13 * 1024 * 1024);

  cast4_kernel<<<dim3(64, 4), 256, 0, stream>>>(W1c, W2c, W1k, W2k, wq);

  mlp_norm_kernel<<<dim3(NROWS / 64, 2), 256, 0, stream>>>(
      z1, z2, wq, b1c, b2c, b1k, b2k, aU, bU);

  lse_kernel<<<dim3(4096), 256, 0, stream>>>(aU, bU, partial);

  row_reduce_kernel<<<128, 256, 0, stream>>>(partial, aU, bU, blocksum);
  final_kernel<<<1, 128, 0, stream>>>(blocksum, (float*)d_out);
}